// Round 6
// baseline (54.465 us; speedup 1.0000x reference)
//
#include <hip/hip_runtime.h>

typedef __attribute__((ext_vector_type(4))) float f32x4;
typedef __attribute__((ext_vector_type(8))) __bf16 bf16x8;
typedef __attribute__((ext_vector_type(8))) unsigned short ushort8v;

#define NGRP   100
#define DDIM   768
#define FDIM   100
#define NCLS   10000
#define NSTEP  12                       // 768 / 64
#define NTILE  7                        // ceil(112/16) f-tiles
#define NCHUNK 14                       // 7 f-tiles x 2 k-halves
#define CH_SHORTS 512                   // one chunk: 64 lanes x 8 bf16 (16 B/lane)
#define STEP_SHORTS (NCHUNK * CH_SHORTS)   // 7168 shorts = 14336 B per k-step
#define G_SHORTS (NSTEP * STEP_SHORTS)     // 86016 shorts per group (168 KB)

static __device__ __forceinline__ unsigned short f2bf(float f) {
    __bf16 b = (__bf16)f;   // RNE; pairs into v_cvt_pk_bf16_f32
    return __builtin_bit_cast(unsigned short, b);
}

// ---- pre-pass: W (g,d,f) f32 -> Wt fragment-linear bf16 (unchanged, verified) ----
// Wt[g][step][c][lane][j] = W[g][step*64 + (c&1)*32 + (lane>>4)*8 + j][min((c>>1)*16 + (lane&15), 99)]
__global__ __launch_bounds__(256) void build_wt(
    const float* __restrict__ W, unsigned short* __restrict__ Wt)
{
    __shared__ unsigned short lt[FDIM * 66];   // [f][d-offset], 33-dword stride: conflict-free
    const int b = blockIdx.x, g = b / 12, step = b % 12;
    const int tid = threadIdx.x;

    const float* Wg = W + (size_t)g * (DDIM * FDIM) + (size_t)step * 64 * FDIM;
#pragma unroll
    for (int j = 0; j < 25; ++j) {          // 64 d-rows x 100 f, coalesced reads
        const int i = tid + j * 256;
        const int r = i / 100, f = i % 100;
        lt[f * 66 + r] = f2bf(Wg[i]);
    }
    __syncthreads();

    unsigned short* out = Wt + (size_t)g * G_SHORTS + step * STEP_SHORTS;
#pragma unroll
    for (int j = 0; j < 4; ++j) {
        const int idx = tid + j * 256;      // 0..895 fragment-lane slots
        if (idx < NCHUNK * 64) {
            const int c = idx >> 6, lane = idx & 63;
            const int t = c >> 1, half = c & 1;
            int f = t * 16 + (lane & 15); if (f > FDIM - 1) f = FDIM - 1;
            const int kk = half * 32 + (lane >> 4) * 8;
            const unsigned short* src = &lt[f * 66 + kk];
            ushort8v v;
            v[0]=src[0]; v[1]=src[1]; v[2]=src[2]; v[3]=src[3];
            v[4]=src[4]; v[5]=src[5]; v[6]=src[6]; v[7]=src[7];
            *(ushort8v*)(out + (size_t)idx * 8) = v;    // coalesced 16B stores
        }
    }
}

// ---- main: 1 wave per block, NO LDS, NO barriers; explicit reg double-buffers ----
// B from fragment-linear Wt: coalesced 16B/lane, L2-resident. A dist-2, B dist-1.
__global__ __launch_bounds__(64, 2) void gfcp_main(
    const float* __restrict__ H, const unsigned short* __restrict__ Wt,
    const float* __restrict__ Bv, float* __restrict__ Out)
{
    // 3200 blocks = 100 groups x 32 wave-units of 16 rows. 3200 % 8 == 0.
    // XCD-bijective swizzle: each XCD gets 400 contiguous wgids = 12.5 groups (Wt 2.1 MB in L2).
    const int bid  = blockIdx.x;
    const int wgid = (bid & 7) * 400 + (bid >> 3);
    const int g    = wgid >> 5;           // group 0..99
    const int m0   = (wgid & 31) * 16;    // row block 0..496

    const int lane = threadIdx.x & 63;
    const int r16  = lane & 15;
    const int kg   = lane >> 4;

    const float* Ap = H + (size_t)(m0 + r16) * (NGRP * DDIM)
                        + (size_t)g * DDIM + kg * 8;
    const unsigned short* Bg = Wt + (size_t)g * G_SHORTS + lane * 8;

    f32x4 acc[NTILE];
#pragma unroll
    for (int t = 0; t < NTILE; ++t) acc[t] = (f32x4)(0.0f);

    f32x4 a0[4], a1[4];          // A slots, distance 2 (HBM latency cover)
    ushort8v b0[NCHUNK], b1[NCHUNK];   // B slots, distance 1 (L2 latency cover)

#define LOADA(SL, STEP) do { \
        const float* p_ = Ap + (STEP) * 64; \
        SL[0] = *(const f32x4*)(p_); \
        SL[1] = *(const f32x4*)(p_ + 4); \
        SL[2] = *(const f32x4*)(p_ + 32); \
        SL[3] = *(const f32x4*)(p_ + 36); \
    } while (0)

#define LOADB(SL, STEP) do { \
        const unsigned short* q_ = Bg + (STEP) * STEP_SHORTS; \
        _Pragma("unroll") \
        for (int c_ = 0; c_ < NCHUNK; ++c_) \
            SL[c_] = *(const ushort8v*)(q_ + c_ * CH_SHORTS); \
    } while (0)

#define COMPUTE(ASL, BSL) do { \
        _Pragma("unroll") \
        for (int s_ = 0; s_ < 2; ++s_) { \
            ushort8v u_; \
            _Pragma("unroll") \
            for (int j_ = 0; j_ < 4; ++j_) { \
                u_[j_]     = f2bf(ASL[2*s_][j_]); \
                u_[j_ + 4] = f2bf(ASL[2*s_+1][j_]); \
            } \
            const bf16x8 af_ = __builtin_bit_cast(bf16x8, u_); \
            _Pragma("unroll") \
            for (int t_ = 0; t_ < NTILE; ++t_) { \
                acc[t_] = __builtin_amdgcn_mfma_f32_16x16x32_bf16( \
                    af_, __builtin_bit_cast(bf16x8, BSL[t_ * 2 + s_]), acc[t_], 0, 0, 0); \
            } \
        } \
    } while (0)

    // prologue: A dist-2, B dist-1
    LOADA(a0, 0);
    LOADA(a1, 1);
    LOADB(b0, 0);

#pragma unroll
    for (int t = 0; t < NSTEP; ++t) {
        if (t + 1 < NSTEP) {
            if ((t & 1) == 0) LOADB(b1, t + 1); else LOADB(b0, t + 1);
        }
        if ((t & 1) == 0) {
            COMPUTE(a0, b0);
            if (t + 2 < NSTEP) LOADA(a0, t + 2);
        } else {
            COMPUTE(a1, b1);
            if (t + 2 < NSTEP) LOADA(a1, t + 2);
        }
    }

    // epilogue: C/D layout col=lane&15, row=(lane>>4)*4+r
    const int orow  = m0 + kg * 4;
    const int fbase = g * FDIM;
#pragma unroll
    for (int t = 0; t < NTILE; ++t) {
        const int fc = t * 16 + r16;
        if (fc < FDIM) {
            const float bv = Bv[fbase + fc];
#pragma unroll
            for (int r = 0; r < 4; ++r) {
                Out[(size_t)(orow + r) * NCLS + fbase + fc] = acc[t][r] + bv;
            }
        }
    }
}

extern "C" void kernel_launch(void* const* d_in, const int* in_sizes, int n_in,
                              void* d_out, int out_size, void* d_ws, size_t ws_size,
                              hipStream_t stream) {
    const float* H  = (const float*)d_in[0];   // (512, 100, 768) f32
    const float* W  = (const float*)d_in[1];   // (100, 768, 100) f32
    const float* Bv = (const float*)d_in[2];   // (10000,) f32
    float* Out = (float*)d_out;                // (512, 10000) f32
    unsigned short* Wt = (unsigned short*)d_ws; // fragment-linear bf16, 17.2 MB

    build_wt<<<dim3(1200), dim3(256), 0, stream>>>(W, Wt);
    gfcp_main<<<dim3(3200), dim3(64), 0, stream>>>(H, Wt, Bv, Out);
}